// Round 3
// baseline (1462.532 us; speedup 1.0000x reference)
//
#include <hip/hip_runtime.h>
#include <math.h>

#define BB 8
#define CC 256
#define NN 2048

static const size_t NC  = (size_t)NN * CC;   // 524288 (== CN, square-ish)
static const size_t CN  = (size_t)CC * NN;
static const size_t XBS = 3 * CN;            // batch stride of x [B,3,C,N]

typedef unsigned short u16;
typedef __attribute__((ext_vector_type(8))) short short8;   // 8 bf16 (one MFMA frag)
typedef __attribute__((ext_vector_type(4))) float f32x4;    // MFMA acc

__device__ __forceinline__ float bf2f(u16 v) {
    union { unsigned int u; float f; } t; t.u = ((unsigned int)v) << 16; return t.f;
}
__device__ __forceinline__ u16 f2bf(float f) {
    union { float f; unsigned int u; } t; t.f = f;
    return (u16)((t.u + 0x7fffu + ((t.u >> 16) & 1u)) >> 16);
}
__device__ __forceinline__ float sigf(float x) { return 1.0f / (1.0f + expf(-x)); }

// ---------------------------------------------------------------------------
// cast fp32 -> bf16 (weights)
// ---------------------------------------------------------------------------
__global__ __launch_bounds__(256) void cast_kernel(const float* __restrict__ in,
                                                   u16* __restrict__ out)
{
    const size_t i = ((size_t)blockIdx.x * 256 + threadIdx.x) * 4;
    const float4 v = *(const float4*)&in[i];
    ushort4 p;
    p.x = f2bf(v.x); p.y = f2bf(v.y); p.z = f2bf(v.z); p.w = f2bf(v.w);
    *(ushort4*)&out[i] = p;
}

// ---------------------------------------------------------------------------
// transpose-cast x: Xt[z][n][c] = bf16(x[z][c][n]); z = b*3+slice
// ---------------------------------------------------------------------------
__global__ __launch_bounds__(256) void tcast_x(const float* __restrict__ in,
                                               u16* __restrict__ out)
{
    const int z = blockIdx.z;
    const float* I = in + (size_t)z * CN;
    u16* O = out + (size_t)z * NC;
    const int c0 = blockIdx.y * 64, n0 = blockIdx.x * 64;
    const int tx = threadIdx.x & 15, ty = threadIdx.x >> 4;

    __shared__ float t[64][68];

    #pragma unroll
    for (int cc = 0; cc < 64; cc += 16) {
        const int c = ty + cc;
        *(float4*)&t[c][tx * 4] = *(const float4*)&I[(size_t)(c0 + c) * NN + n0 + tx * 4];
    }
    __syncthreads();
    #pragma unroll
    for (int nn2 = 0; nn2 < 64; nn2 += 16) {
        const int n = ty + nn2;
        ushort4 p;
        p.x = f2bf(t[tx * 4 + 0][n]);
        p.y = f2bf(t[tx * 4 + 1][n]);
        p.z = f2bf(t[tx * 4 + 2][n]);
        p.w = f2bf(t[tx * 4 + 3][n]);
        *(ushort4*)&O[(size_t)(n0 + n) * CC + c0 + tx * 4] = p;
    }
}

// ---------------------------------------------------------------------------
// transpose-cast with subtract: dt[mod][b][n][c] = bf16(x[b][xs][c][n] - XR[mod][b][c][n])
// ---------------------------------------------------------------------------
struct TcastP { const float* xsrc[5]; const float* xr[5]; u16* dt[5]; };

__global__ __launch_bounds__(256) void tcast_sub(TcastP P)
{
    const int z = blockIdx.z, mod = z >> 3, b = z & 7;
    const float* I = P.xsrc[mod] + (size_t)b * XBS;
    const float* S = P.xr[mod]   + (size_t)b * CN;
    u16* O = P.dt[mod] + (size_t)b * NC;
    const int c0 = blockIdx.y * 64, n0 = blockIdx.x * 64;
    const int tx = threadIdx.x & 15, ty = threadIdx.x >> 4;

    __shared__ float t[64][68];

    #pragma unroll
    for (int cc = 0; cc < 64; cc += 16) {
        const int c = ty + cc;
        const size_t g = (size_t)(c0 + c) * NN + n0 + tx * 4;
        float4 v = *(const float4*)&I[g];
        const float4 s = *(const float4*)&S[g];
        v.x -= s.x; v.y -= s.y; v.z -= s.z; v.w -= s.w;
        *(float4*)&t[c][tx * 4] = v;
    }
    __syncthreads();
    #pragma unroll
    for (int nn2 = 0; nn2 < 64; nn2 += 16) {
        const int n = ty + nn2;
        ushort4 p;
        p.x = f2bf(t[tx * 4 + 0][n]);
        p.y = f2bf(t[tx * 4 + 1][n]);
        p.z = f2bf(t[tx * 4 + 2][n]);
        p.w = f2bf(t[tx * 4 + 3][n]);
        *(ushort4*)&O[(size_t)(n0 + n) * CC + c0 + tx * 4] = p;
    }
}

// ---------------------------------------------------------------------------
// Q/K/V conv via MFMA, table-driven. Per job: isv=0 -> out bf16 [N][C]
// (transposed, for attn); isv=1 -> out bf16 [C][N] + bias (for PV).
// Tile 128c x 128n, 4 waves, 4x4 frags/wave. z = job*8 + b.
// ---------------------------------------------------------------------------
struct QkvP {
    const u16* w[12]; const u16* x[12]; u16* out[12];
    const float* bias[12]; int isv[12];
};

__global__ __launch_bounds__(256) void conv_qkv(QkvP P)
{
    const int z = blockIdx.z, job = z >> 3, b = z & 7;
    const u16* W  = P.w[job];
    const u16* Xp = P.x[job] + (size_t)b * (3 * NC);
    const int n0 = blockIdx.x * 128, c0 = blockIdx.y * 128;
    const int lane = threadIdx.x & 63, wave = threadIdx.x >> 6;
    const int wc = (wave >> 1) * 64, wn = (wave & 1) * 64;
    const int l15 = lane & 15, lk = (lane >> 4) * 8;

    f32x4 acc[4][4] = {};
    const u16* wrow[4]; const u16* xrow[4];
    #pragma unroll
    for (int ai = 0; ai < 4; ai++) wrow[ai] = W  + (size_t)(c0 + wc + ai * 16 + l15) * CC + lk;
    #pragma unroll
    for (int bj = 0; bj < 4; bj++) xrow[bj] = Xp + (size_t)(n0 + wn + bj * 16 + l15) * CC + lk;

    #pragma unroll 2
    for (int kc = 0; kc < 8; kc++) {
        short8 a[4], bf[4];
        #pragma unroll
        for (int ai = 0; ai < 4; ai++) a[ai]  = *(const short8*)(wrow[ai] + kc * 32);
        #pragma unroll
        for (int bj = 0; bj < 4; bj++) bf[bj] = *(const short8*)(xrow[bj] + kc * 32);
        #pragma unroll
        for (int ai = 0; ai < 4; ai++)
            #pragma unroll
            for (int bj = 0; bj < 4; bj++)
                acc[ai][bj] = __builtin_amdgcn_mfma_f32_16x16x32_bf16(a[ai], bf[bj], acc[ai][bj], 0, 0, 0);
    }

    if (!P.isv[job]) {
        u16* Ot = P.out[job] + (size_t)b * NC;
        #pragma unroll
        for (int bj = 0; bj < 4; bj++) {
            const int n = n0 + wn + bj * 16 + l15;
            #pragma unroll
            for (int ai = 0; ai < 4; ai++) {
                const int cb = c0 + wc + ai * 16 + (lane >> 4) * 4;
                ushort4 p;
                p.x = f2bf(acc[ai][bj][0]); p.y = f2bf(acc[ai][bj][1]);
                p.z = f2bf(acc[ai][bj][2]); p.w = f2bf(acc[ai][bj][3]);
                *(ushort4*)&Ot[(size_t)n * CC + cb] = p;
            }
        }
    } else {
        u16* Oc = P.out[job] + (size_t)b * CN;
        const float* bias = P.bias[job];
        #pragma unroll
        for (int ai = 0; ai < 4; ai++)
            #pragma unroll
            for (int r = 0; r < 4; r++) {
                const int c = c0 + wc + ai * 16 + (lane >> 4) * 4 + r;
                const float bi = bias[c];
                #pragma unroll
                for (int bj = 0; bj < 4; bj++) {
                    const int n = n0 + wn + bj * 16 + l15;
                    Oc[(size_t)c * NN + n] = f2bf(acc[ai][bj][r] + bi);
                }
            }
    }
}

// ---------------------------------------------------------------------------
// T-stage conv: O[c][n] = xsrc[c][n] + relu(sum_k W[c][k]*Dt[n][k] + bias[c])
// ---------------------------------------------------------------------------
struct TcvP {
    const u16* w[5]; const u16* dt[5]; const float* bias[5];
    const float* xsrc[5]; float* o[5];
};

__global__ __launch_bounds__(256) void conv_t(TcvP P)
{
    const int z = blockIdx.z, mod = z >> 3, b = z & 7;
    const u16* W  = P.w[mod];
    const u16* Xp = P.dt[mod] + (size_t)b * NC;
    const int n0 = blockIdx.x * 128, c0 = blockIdx.y * 128;
    const int lane = threadIdx.x & 63, wave = threadIdx.x >> 6;
    const int wc = (wave >> 1) * 64, wn = (wave & 1) * 64;
    const int l15 = lane & 15, lk = (lane >> 4) * 8;

    f32x4 acc[4][4] = {};
    const u16* wrow[4]; const u16* xrow[4];
    #pragma unroll
    for (int ai = 0; ai < 4; ai++) wrow[ai] = W  + (size_t)(c0 + wc + ai * 16 + l15) * CC + lk;
    #pragma unroll
    for (int bj = 0; bj < 4; bj++) xrow[bj] = Xp + (size_t)(n0 + wn + bj * 16 + l15) * CC + lk;

    #pragma unroll 2
    for (int kc = 0; kc < 8; kc++) {
        short8 a[4], bf[4];
        #pragma unroll
        for (int ai = 0; ai < 4; ai++) a[ai]  = *(const short8*)(wrow[ai] + kc * 32);
        #pragma unroll
        for (int bj = 0; bj < 4; bj++) bf[bj] = *(const short8*)(xrow[bj] + kc * 32);
        #pragma unroll
        for (int ai = 0; ai < 4; ai++)
            #pragma unroll
            for (int bj = 0; bj < 4; bj++)
                acc[ai][bj] = __builtin_amdgcn_mfma_f32_16x16x32_bf16(a[ai], bf[bj], acc[ai][bj], 0, 0, 0);
    }

    float* Of = P.o[mod] + (size_t)b * CN;
    const float* Xr = P.xsrc[mod] + (size_t)b * XBS;
    const float* bias = P.bias[mod];
    #pragma unroll
    for (int ai = 0; ai < 4; ai++)
        #pragma unroll
        for (int r = 0; r < 4; r++) {
            const int c = c0 + wc + ai * 16 + (lane >> 4) * 4 + r;
            const float bi = bias[c];
            #pragma unroll
            for (int bj = 0; bj < 4; bj++) {
                const int n = n0 + wn + bj * 16 + l15;
                Of[(size_t)c * NN + n] = Xr[(size_t)c * NN + n] + fmaxf(acc[ai][bj][r] + bi, 0.0f);
            }
        }
}

// ---------------------------------------------------------------------------
// attention v2: 16 q-rows/block, 1024 thr (16 waves), logits in registers.
// Wave w owns m in [w*128, w*128+128) as 8 independent MFMA chains.
// Softmax: shfl-xor lane reduce + 1KiB LDS cross-wave reduce.
// S written from registers, blocked [b][n>>3][m][n&7] -> fully coalesced.
// cspart from registers via shfl (deterministic).
// ---------------------------------------------------------------------------
struct AttnP { const u16* q[5]; const u16* k[5]; u16* s[5]; float* cp[5]; };

__global__ __launch_bounds__(1024) void attn_mfma2(AttnP P)
{
    const int z = blockIdx.y, mod = z >> 3, b = z & 7;
    const int n0 = blockIdx.x * 16;
    const int tid = threadIdx.x, lane = tid & 63, wave = tid >> 6;
    const int l15 = lane & 15, lg = lane >> 4, rb = lg * 4, lk = lg * 8;

    const u16* Qt = P.q[mod] + (size_t)b * NC;
    const u16* Kt = P.k[mod] + (size_t)b * NC;

    short8 a[8];
    {
        const u16* qp = Qt + (size_t)(n0 + l15) * CC + lk;
        #pragma unroll
        for (int kc = 0; kc < 8; kc++) a[kc] = *(const short8*)(qp + kc * 32);
    }

    f32x4 acc[8];
    #pragma unroll
    for (int t = 0; t < 8; t++) acc[t] = (f32x4){0.f, 0.f, 0.f, 0.f};

    const u16* kp = Kt + (size_t)(wave * 128 + l15) * CC + lk;
    for (int kc = 0; kc < 8; kc++) {
        short8 bf[8];
        #pragma unroll
        for (int t = 0; t < 8; t++)
            bf[t] = *(const short8*)(kp + (size_t)t * 16 * CC + kc * 32);
        #pragma unroll
        for (int t = 0; t < 8; t++)
            acc[t] = __builtin_amdgcn_mfma_f32_16x16x32_bf16(a[kc], bf[t], acc[t], 0, 0, 0);
    }

    __shared__ float red[16][16];
    __shared__ float rowstat[16];

    // row max (lane part over 8 tiles, then across the 16-lane m-group)
    float pm[4];
    #pragma unroll
    for (int r = 0; r < 4; r++) {
        float m = acc[0][r];
        #pragma unroll
        for (int t = 1; t < 8; t++) m = fmaxf(m, acc[t][r]);
        #pragma unroll
        for (int o = 1; o <= 8; o <<= 1) m = fmaxf(m, __shfl_xor(m, o));
        pm[r] = m;
    }
    if (l15 == 0) {
        #pragma unroll
        for (int r = 0; r < 4; r++) red[wave][rb + r] = pm[r];
    }
    __syncthreads();
    if (tid < 16) {
        float m = red[0][tid];
        #pragma unroll
        for (int w = 1; w < 16; w++) m = fmaxf(m, red[w][tid]);
        rowstat[tid] = m;
    }
    __syncthreads();

    float rm[4], ps[4];
    #pragma unroll
    for (int r = 0; r < 4; r++) { rm[r] = rowstat[rb + r]; ps[r] = 0.0f; }

    // exp in place + row-sum partials
    #pragma unroll
    for (int t = 0; t < 8; t++)
        #pragma unroll
        for (int r = 0; r < 4; r++) {
            const float e = __expf(acc[t][r] - rm[r]);
            acc[t][r] = e; ps[r] += e;
        }
    #pragma unroll
    for (int r = 0; r < 4; r++)
        #pragma unroll
        for (int o = 1; o <= 8; o <<= 1) ps[r] += __shfl_xor(ps[r], o);
    if (l15 == 0) {
        #pragma unroll
        for (int r = 0; r < 4; r++) red[wave][rb + r] = ps[r];
    }
    __syncthreads();
    if (tid < 16) {
        float s = red[0][tid];
        #pragma unroll
        for (int w = 1; w < 16; w++) s += red[w][tid];
        rowstat[tid] = 1.0f / s;
    }
    __syncthreads();

    float rv[4];
    #pragma unroll
    for (int r = 0; r < 4; r++) rv[r] = rowstat[rb + r];

    // blocked S store: rows rb..rb+3 pack into one 8B store at [m][rb&7]
    u16* sb = P.s[mod] + (size_t)b * (NN / 8) * NN * 8
              + (size_t)((n0 >> 3) + (rb >> 3)) * (NN * 8) + (rb & 7);
    float* cpb = P.cp[mod] + ((size_t)b * 128 + blockIdx.x) * NN;

    #pragma unroll
    for (int t = 0; t < 8; t++) {
        const int m = wave * 128 + t * 16 + l15;
        const float v0 = acc[t][0] * rv[0], v1 = acc[t][1] * rv[1];
        const float v2 = acc[t][2] * rv[2], v3 = acc[t][3] * rv[3];
        ushort4 pk;
        pk.x = f2bf(v0); pk.y = f2bf(v1); pk.z = f2bf(v2); pk.w = f2bf(v3);
        *(ushort4*)&sb[(size_t)m * 8] = pk;
        float cs = v0 + v1 + v2 + v3;
        cs += __shfl_xor(cs, 16);
        cs += __shfl_xor(cs, 32);
        if (lane < 16) cpb[m] = cs;
    }
}

// ---------------------------------------------------------------------------
// colsum[b][m] = sum_{g<128} cspart[b][g][m]
// ---------------------------------------------------------------------------
struct CsP { const float* cp[5]; float* cs[5]; };

__global__ __launch_bounds__(256) void csum_kernel(CsP P)
{
    const int z = blockIdx.y, mod = z >> 3, b = z & 7;
    const int ml = threadIdx.x & 63;
    const int m  = blockIdx.x * 64 + ml;
    const int g0 = threadIdx.x >> 6;
    float s = 0.0f;
    for (int g = g0; g < 128; g += 4)
        s += P.cp[mod][((size_t)b * 128 + g) * NN + m];
    __shared__ float red[4][64];
    red[g0][ml] = s;
    __syncthreads();
    if (threadIdx.x < 64) {
        P.cs[mod][(size_t)b * NN + blockIdx.x * 64 + threadIdx.x] =
            red[0][threadIdx.x] + red[1][threadIdx.x] +
            red[2][threadIdx.x] + red[3][threadIdx.x];
    }
}

// ---------------------------------------------------------------------------
// pv: XR[c][m] = (sum_n V[c][n]*S[n][m]) / (1e-7 + colsum[m])
// ---------------------------------------------------------------------------
struct PvP { const u16* v[5]; const u16* s[5]; const float* cs[5]; float* xr[5]; };

__global__ __launch_bounds__(256) void pv_mfma(PvP P)
{
    const int z = blockIdx.z, mod = z >> 3, b = z & 7;
    const int m0b = blockIdx.x * 64, c0 = blockIdx.y * 128;
    const int lane = threadIdx.x & 63, wave = threadIdx.x >> 6;
    const int wc = (wave >> 1) * 64, wm = (wave & 1) * 32;
    const int l15 = lane & 15, lg = lane >> 4;

    const u16* Vm = P.v[mod] + (size_t)b * CN;
    const u16* Sm = P.s[mod] + (size_t)b * (NN / 8) * NN * 8;

    f32x4 acc[4][2] = {};
    const u16* vp[4]; const u16* sp[2];
    #pragma unroll
    for (int ai = 0; ai < 4; ai++)
        vp[ai] = Vm + (size_t)(c0 + wc + ai * 16 + l15) * NN + lg * 8;
    #pragma unroll
    for (int bj = 0; bj < 2; bj++)
        sp[bj] = Sm + ((size_t)lg * NN + m0b + wm + bj * 16 + l15) * 8;

    #pragma unroll 2
    for (int kc = 0; kc < 64; kc++) {
        short8 a[4], s2[2];
        #pragma unroll
        for (int ai = 0; ai < 4; ai++) { a[ai] = *(const short8*)vp[ai]; vp[ai] += 32; }
        #pragma unroll
        for (int bj = 0; bj < 2; bj++) { s2[bj] = *(const short8*)sp[bj]; sp[bj] += (size_t)4 * NN * 8; }
        #pragma unroll
        for (int ai = 0; ai < 4; ai++)
            #pragma unroll
            for (int bj = 0; bj < 2; bj++)
                acc[ai][bj] = __builtin_amdgcn_mfma_f32_16x16x32_bf16(a[ai], s2[bj], acc[ai][bj], 0, 0, 0);
    }

    #pragma unroll
    for (int bj = 0; bj < 2; bj++) {
        const int m = m0b + wm + bj * 16 + l15;
        const float inv = 1.0f / (1e-7f + P.cs[mod][(size_t)b * NN + m]);
        #pragma unroll
        for (int ai = 0; ai < 4; ai++) {
            const int cb = c0 + wc + ai * 16 + lg * 4;
            #pragma unroll
            for (int r = 0; r < 4; r++)
                P.xr[mod][((size_t)b * CC + cb + r) * NN + m] = acc[ai][bj][r] * inv;
        }
    }
}

// ---------------------------------------------------------------------------
// elementwise combines
// ---------------------------------------------------------------------------
__global__ __launch_bounds__(256) void ew_update_kernel(float* __restrict__ A,
                                                        const float* __restrict__ Bv)
{
    const size_t i = ((size_t)blockIdx.x * 256 + threadIdx.x) * 4;
    float4 a = *(float4*)&A[i];
    const float4 b = *(const float4*)&Bv[i];
    a.x = tanhf(a.x * sigf(b.x));
    a.y = tanhf(a.y * sigf(b.y));
    a.z = tanhf(a.z * sigf(b.z));
    a.w = tanhf(a.w * sigf(b.w));
    *(float4*)&A[i] = a;
}

__global__ __launch_bounds__(256) void ew_final_kernel(const float* __restrict__ TU,
                                                       const float* __restrict__ SU,
                                                       const float* __restrict__ x,
                                                       float* __restrict__ OUT)
{
    const size_t i   = ((size_t)blockIdx.x * 256 + threadIdx.x) * 4;
    const size_t b   = i / CN;
    const size_t off = i - b * CN;
    const float4 mid = *(const float4*)&x[(b * 3 + 1) * CN + off];
    const float4 g   = *(const float4*)&OUT[i];
    const float4 tu  = *(const float4*)&TU[i];
    const float4 su  = *(const float4*)&SU[i];
    float4 o;
    o.x = mid.x + sigf((tu.x + su.x) * sigf(g.x)) * tanhf(g.x);
    o.y = mid.y + sigf((tu.y + su.y) * sigf(g.y)) * tanhf(g.y);
    o.z = mid.z + sigf((tu.z + su.z) * sigf(g.z)) * tanhf(g.z);
    o.w = mid.w + sigf((tu.w + su.w) * sigf(g.w)) * tanhf(g.w);
    *(float4*)&OUT[i] = o;
}

// ---------------------------------------------------------------------------
extern "C" void kernel_launch(void* const* d_in, const int* in_sizes, int n_in,
                              void* d_out, int out_size, void* d_ws, size_t ws_size,
                              hipStream_t stream)
{
    const float* x   = (const float*)d_in[0];
    const float* Wqk = (const float*)d_in[1];
    const float* Vw  = (const float*)d_in[2];
    const float* VbF = (const float*)d_in[3];
    const float* Tw  = (const float*)d_in[4];
    const float* TbF = (const float*)d_in[5];
    float* out = (float*)d_out;

    // module meta: x-side slice (K,V) and y-side slice (Q). time=0 mid=1 space=2
    const int mxs[5] = {0, 2, 0, 2, 1};
    const int mys[5] = {0, 2, 2, 0, 1};
    const int qjob[5] = {0, 1, 5, 6, 4};           // tier A/B: Q slab per module
    const int q_wi[7] = {0, 1, 2, 3, 4, 2, 3};     // jobs 0-4: K_i; 5: Q2; 6: Q3
    const int q_xi[7] = {0, 2, 0, 2, 1, 2, 0};

    const size_t WSZ     = (size_t)CC * CC;              // 65536 elems
    const size_t QK_SLAB = (size_t)BB * NC;              // elems (bf16)
    const size_t S_SLAB  = (size_t)BB * NN * NN;         // elems (bf16)
    const size_t CP_SLAB = (size_t)BB * 128 * NN;        // elems (f32)
    const size_t CS_SLAB = (size_t)BB * NN;
    const size_t XR_SLAB = (size_t)BB * CN;
    const size_t O_SLAB  = (size_t)BB * CN;

    const size_t base_b = 15 * WSZ * 2 + (size_t)BB * 3 * NC * 2;
    const size_t mod_b  = S_SLAB * 2 + CP_SLAB * 4 + CS_SLAB * 4 + XR_SLAB * 4 + QK_SLAB * 2 /*Dt*/;
    const size_t margin = 2u << 20;
    const size_t need_A = base_b + 12 * QK_SLAB * 2 + 5 * mod_b + 4 * O_SLAB * 4 + margin;
    const size_t need_B = base_b + 12 * QK_SLAB * 2 + 1 * mod_b + 2 * O_SLAB * 4 + margin;
    const size_t need_C = base_b +  3 * QK_SLAB * 2 + 1 * mod_b + 2 * O_SLAB * 4 + margin;

    const int tier = (ws_size >= need_A) ? 0 : (ws_size >= need_B ? 1 : 2);
    if (tier == 2 && ws_size < need_C) return;   // can't run: leave poison (loud failure)

    const int nQK = (tier <= 1) ? 7 : 2;
    const int nV  = (tier <= 1) ? 5 : 1;
    const int nM  = (tier == 0) ? 5 : 1;
    const int nO  = (tier == 0) ? 4 : 2;

    char* ws = (char*)d_ws;
    size_t off = 0;
    auto alloc = [&](size_t bytes) -> char* {
        char* p = ws + off; off += (bytes + 255) & ~255ULL; return p;
    };

    u16*   W16 = (u16*)  alloc(15 * WSZ * 2);
    u16*   Xt  = (u16*)  alloc((size_t)BB * 3 * NC * 2);
    u16*   QK  = (u16*)  alloc((size_t)nQK * QK_SLAB * 2);
    u16*   VB  = (u16*)  alloc((size_t)nV * QK_SLAB * 2);
    u16*   S   = (u16*)  alloc((size_t)nM * S_SLAB * 2);
    float* CP  = (float*)alloc((size_t)nM * CP_SLAB * 4);
    float* CS  = (float*)alloc((size_t)nM * CS_SLAB * 4);
    float* XR  = (float*)alloc((size_t)nM * XR_SLAB * 4);
    u16*   DT  = (u16*)  alloc((size_t)nM * QK_SLAB * 2);
    float* OB  = (float*)alloc((size_t)nO * O_SLAB * 4);

    // ---- weights -> bf16, x -> Xt bf16 [B*3][N][C] ----
    cast_kernel<<<320, 256, 0, stream>>>(Wqk, W16);
    cast_kernel<<<320, 256, 0, stream>>>(Vw,  W16 + 5 * WSZ);
    cast_kernel<<<320, 256, 0, stream>>>(Tw,  W16 + 10 * WSZ);
    tcast_x<<<dim3(NN / 64, CC / 64, BB * 3), 256, 0, stream>>>(x, Xt);

    const dim3 convG(NN / 128, CC / 128, 1);   // z set per launch
    // per-stage tail over a module set [m0, m0+nm)
    auto run_tail = [&](int m0, int nm,
                        const u16* qv[5], const u16* kv[5], const u16* vv[5],
                        u16* sv[5], float* cpv[5], float* csv[5], float* xrv[5],
                        u16* dtv[5], float* ov[5]) {
        AttnP ap{}; CsP cp{}; PvP pp{}; TcastP tp{}; TcvP tv{};
        for (int j = 0; j < nm; j++) {
            const int i = m0 + j;
            ap.q[j] = qv[j]; ap.k[j] = kv[j]; ap.s[j] = sv[j]; ap.cp[j] = cpv[j];
            cp.cp[j] = cpv[j]; cp.cs[j] = csv[j];
            pp.v[j] = vv[j]; pp.s[j] = sv[j]; pp.cs[j] = csv[j]; pp.xr[j] = xrv[j];
            tp.xsrc[j] = x + (size_t)mxs[i] * CN; tp.xr[j] = xrv[j]; tp.dt[j] = dtv[j];
            tv.w[j] = W16 + (size_t)(10 + i) * WSZ; tv.dt[j] = dtv[j];
            tv.bias[j] = TbF + (size_t)i * CC;
            tv.xsrc[j] = x + (size_t)mxs[i] * CN; tv.o[j] = ov[j];
        }
        attn_mfma2<<<dim3(NN / 16, 8 * nm), 1024, 0, stream>>>(ap);
        csum_kernel<<<dim3(NN / 64, 8 * nm), 256, 0, stream>>>(cp);
        pv_mfma<<<dim3(NN / 64, CC / 128, 8 * nm), 256, 0, stream>>>(pp);
        tcast_sub<<<dim3(NN / 64, CC / 64, 8 * nm), 256, 0, stream>>>(tp);
        conv_t<<<dim3(NN / 128, CC / 128, 8 * nm), 256, 0, stream>>>(tv);
    };

    if (tier <= 1) {
        // ---- all 12 QKV convs in one launch ----
        QkvP qp{};
        for (int j = 0; j < 7; j++) {
            qp.w[j] = W16 + (size_t)q_wi[j] * WSZ;
            qp.x[j] = Xt + (size_t)q_xi[j] * NC;
            qp.out[j] = QK + (size_t)j * QK_SLAB;
            qp.isv[j] = 0; qp.bias[j] = nullptr;
        }
        for (int i = 0; i < 5; i++) {
            const int j = 7 + i;
            qp.w[j] = W16 + (size_t)(5 + i) * WSZ;
            qp.x[j] = Xt + (size_t)mxs[i] * NC;
            qp.out[j] = VB + (size_t)i * QK_SLAB;
            qp.isv[j] = 1; qp.bias[j] = VbF + (size_t)i * CC;
        }
        conv_qkv<<<dim3(NN / 128, CC / 128, 96), 256, 0, stream>>>(qp);
    }

    if (tier == 0) {
        const u16* qv[5]; const u16* kv[5]; const u16* vv[5];
        u16* sv[5]; float* cpv[5]; float* csv[5]; float* xrv[5];
        u16* dtv[5]; float* ov[5];
        for (int i = 0; i < 5; i++) {
            qv[i] = QK + (size_t)qjob[i] * QK_SLAB;
            kv[i] = QK + (size_t)i * QK_SLAB;
            vv[i] = VB + (size_t)i * QK_SLAB;
            sv[i] = S + (size_t)i * S_SLAB;
            cpv[i] = CP + (size_t)i * CP_SLAB;
            csv[i] = CS + (size_t)i * CS_SLAB;
            xrv[i] = XR + (size_t)i * XR_SLAB;
            dtv[i] = DT + (size_t)i * QK_SLAB;
            ov[i] = (i < 4) ? (OB + (size_t)i * O_SLAB) : out;
        }
        run_tail(0, 5, qv, kv, vv, sv, cpv, csv, xrv, dtv, ov);
        ew_update_kernel<<<4096, 256, 0, stream>>>(OB + 0 * O_SLAB, OB + 2 * O_SLAB);
        ew_update_kernel<<<4096, 256, 0, stream>>>(OB + 1 * O_SLAB, OB + 3 * O_SLAB);
        ew_final_kernel<<<4096, 256, 0, stream>>>(OB + 0 * O_SLAB, OB + 1 * O_SLAB, x, out);
        return;
    }

    // ---- tier 1/2: per-module tail (shared S etc.), tier 2 also per-module convs ----
    auto run_mod = [&](int i, float* O) {
        const u16* Qp; const u16* Kp; const u16* Vp;
        if (tier == 1) {
            Qp = QK + (size_t)qjob[i] * QK_SLAB;
            Kp = QK + (size_t)i * QK_SLAB;
            Vp = VB + (size_t)i * QK_SLAB;
        } else {
            QkvP qp{}; int nj = 0;
            qp.w[nj] = W16 + (size_t)i * WSZ; qp.x[nj] = Xt + (size_t)mxs[i] * NC;
            qp.out[nj] = QK; qp.isv[nj] = 0; nj++;
            Qp = QK; Kp = QK;
            if (mys[i] != mxs[i]) {
                qp.w[nj] = W16 + (size_t)i * WSZ; qp.x[nj] = Xt + (size_t)mys[i] * NC;
                qp.out[nj] = QK + QK_SLAB; qp.isv[nj] = 0; nj++;
                Qp = QK + QK_SLAB;
            }
            qp.w[nj] = W16 + (size_t)(5 + i) * WSZ; qp.x[nj] = Xt + (size_t)mxs[i] * NC;
            qp.out[nj] = VB; qp.isv[nj] = 1; qp.bias[nj] = VbF + (size_t)i * CC; nj++;
            conv_qkv<<<dim3(NN / 128, CC / 128, 8 * nj), 256, 0, stream>>>(qp);
            Vp = VB;
        }
        const u16* qv[5] = {Qp}; const u16* kv[5] = {Kp}; const u16* vv[5] = {Vp};
        u16* sv[5] = {S}; float* cpv[5] = {CP}; float* csv[5] = {CS};
        float* xrv[5] = {XR}; u16* dtv[5] = {DT}; float* ov[5] = {O};
        run_tail(i, 1, qv, kv, vv, sv, cpv, csv, xrv, dtv, ov);
    };

    run_mod(0, OB);                                          // time_att
    run_mod(2, OB + O_SLAB);                                 // time_cor
    ew_update_kernel<<<4096, 256, 0, stream>>>(OB, OB + O_SLAB);
    run_mod(1, OB + O_SLAB);                                 // space_att
    run_mod(3, out);                                         // space_cor (d_out temp)
    ew_update_kernel<<<4096, 256, 0, stream>>>(OB + O_SLAB, out);
    run_mod(4, out);                                         // global_feat
    ew_final_kernel<<<4096, 256, 0, stream>>>(OB, OB + O_SLAB, x, out);
}

// Round 4
// 1142.837 us; speedup vs baseline: 1.2797x; 1.2797x over previous
//
#include <hip/hip_runtime.h>
#include <math.h>

#define BB 8
#define CC 256
#define NN 2048

static const size_t NC  = (size_t)NN * CC;
static const size_t CN  = (size_t)CC * NN;
static const size_t XBS = 3 * CN;            // batch stride of x [B,3,C,N]

typedef unsigned short u16;
typedef __attribute__((ext_vector_type(8))) short short8;   // 8 bf16 (one MFMA frag)
typedef __attribute__((ext_vector_type(4))) float f32x4;    // MFMA acc

__device__ __forceinline__ float bf2f(u16 v) {
    union { unsigned int u; float f; } t; t.u = ((unsigned int)v) << 16; return t.f;
}
__device__ __forceinline__ u16 f2bf(float f) {
    union { float f; unsigned int u; } t; t.f = f;
    return (u16)((t.u + 0x7fffu + ((t.u >> 16) & 1u)) >> 16);
}
__device__ __forceinline__ float sigf(float x) { return 1.0f / (1.0f + expf(-x)); }

// ---------------------------------------------------------------------------
// cast fp32 -> bf16 (weights)
// ---------------------------------------------------------------------------
__global__ __launch_bounds__(256) void cast_kernel(const float* __restrict__ in,
                                                   u16* __restrict__ out)
{
    const size_t i = ((size_t)blockIdx.x * 256 + threadIdx.x) * 4;
    const float4 v = *(const float4*)&in[i];
    ushort4 p;
    p.x = f2bf(v.x); p.y = f2bf(v.y); p.z = f2bf(v.z); p.w = f2bf(v.w);
    *(ushort4*)&out[i] = p;
}

// ---------------------------------------------------------------------------
// transpose-cast x: Xt[z][n][c] = bf16(x[z][c][n]); z = b*3+slice
// ---------------------------------------------------------------------------
__global__ __launch_bounds__(256) void tcast_x(const float* __restrict__ in,
                                               u16* __restrict__ out)
{
    const int z = blockIdx.z;
    const float* I = in + (size_t)z * CN;
    u16* O = out + (size_t)z * NC;
    const int c0 = blockIdx.y * 64, n0 = blockIdx.x * 64;
    const int tx = threadIdx.x & 15, ty = threadIdx.x >> 4;

    __shared__ float t[64][68];

    #pragma unroll
    for (int cc = 0; cc < 64; cc += 16) {
        const int c = ty + cc;
        *(float4*)&t[c][tx * 4] = *(const float4*)&I[(size_t)(c0 + c) * NN + n0 + tx * 4];
    }
    __syncthreads();
    #pragma unroll
    for (int nn2 = 0; nn2 < 64; nn2 += 16) {
        const int n = ty + nn2;
        ushort4 p;
        p.x = f2bf(t[tx * 4 + 0][n]);
        p.y = f2bf(t[tx * 4 + 1][n]);
        p.z = f2bf(t[tx * 4 + 2][n]);
        p.w = f2bf(t[tx * 4 + 3][n]);
        *(ushort4*)&O[(size_t)(n0 + n) * CC + c0 + tx * 4] = p;
    }
}

// ---------------------------------------------------------------------------
// Q/K/V conv via MFMA, table-driven. isv=0 -> out bf16 [N][C] (for attn);
// isv=1 -> out bf16 [C][N] + bias (for PV). z = job*8 + b.
// ---------------------------------------------------------------------------
struct QkvP {
    const u16* w[12]; const u16* x[12]; u16* out[12];
    const float* bias[12]; int isv[12];
};

__global__ __launch_bounds__(256) void conv_qkv(QkvP P)
{
    const int z = blockIdx.z, job = z >> 3, b = z & 7;
    const u16* W  = P.w[job];
    const u16* Xp = P.x[job] + (size_t)b * (3 * NC);
    const int n0 = blockIdx.x * 128, c0 = blockIdx.y * 128;
    const int lane = threadIdx.x & 63, wave = threadIdx.x >> 6;
    const int wc = (wave >> 1) * 64, wn = (wave & 1) * 64;
    const int l15 = lane & 15, lk = (lane >> 4) * 8;

    f32x4 acc[4][4] = {};
    const u16* wrow[4]; const u16* xrow[4];
    #pragma unroll
    for (int ai = 0; ai < 4; ai++) wrow[ai] = W  + (size_t)(c0 + wc + ai * 16 + l15) * CC + lk;
    #pragma unroll
    for (int bj = 0; bj < 4; bj++) xrow[bj] = Xp + (size_t)(n0 + wn + bj * 16 + l15) * CC + lk;

    #pragma unroll 2
    for (int kc = 0; kc < 8; kc++) {
        short8 a[4], bf[4];
        #pragma unroll
        for (int ai = 0; ai < 4; ai++) a[ai]  = *(const short8*)(wrow[ai] + kc * 32);
        #pragma unroll
        for (int bj = 0; bj < 4; bj++) bf[bj] = *(const short8*)(xrow[bj] + kc * 32);
        #pragma unroll
        for (int ai = 0; ai < 4; ai++)
            #pragma unroll
            for (int bj = 0; bj < 4; bj++)
                acc[ai][bj] = __builtin_amdgcn_mfma_f32_16x16x32_bf16(a[ai], bf[bj], acc[ai][bj], 0, 0, 0);
    }

    if (!P.isv[job]) {
        u16* Ot = P.out[job] + (size_t)b * NC;
        #pragma unroll
        for (int bj = 0; bj < 4; bj++) {
            const int n = n0 + wn + bj * 16 + l15;
            #pragma unroll
            for (int ai = 0; ai < 4; ai++) {
                const int cb = c0 + wc + ai * 16 + (lane >> 4) * 4;
                ushort4 p;
                p.x = f2bf(acc[ai][bj][0]); p.y = f2bf(acc[ai][bj][1]);
                p.z = f2bf(acc[ai][bj][2]); p.w = f2bf(acc[ai][bj][3]);
                *(ushort4*)&Ot[(size_t)n * CC + cb] = p;
            }
        }
    } else {
        u16* Oc = P.out[job] + (size_t)b * CN;
        const float* bias = P.bias[job];
        #pragma unroll
        for (int ai = 0; ai < 4; ai++)
            #pragma unroll
            for (int r = 0; r < 4; r++) {
                const int c = c0 + wc + ai * 16 + (lane >> 4) * 4 + r;
                const float bi = bias[c];
                #pragma unroll
                for (int bj = 0; bj < 4; bj++) {
                    const int n = n0 + wn + bj * 16 + l15;
                    Oc[(size_t)c * NN + n] = f2bf(acc[ai][bj][r] + bi);
                }
            }
    }
}

// ---------------------------------------------------------------------------
// T-stage conv: O[c][n] = xsrc[c][n] + relu(sum_k W[c][k]*Dt[n][k] + bias[c])
// ---------------------------------------------------------------------------
struct TcvP {
    const u16* w[5]; const u16* dt[5]; const float* bias[5];
    const float* xsrc[5]; float* o[5];
};

__global__ __launch_bounds__(256) void conv_t(TcvP P)
{
    const int z = blockIdx.z, mod = z >> 3, b = z & 7;
    const u16* W  = P.w[mod];
    const u16* Xp = P.dt[mod] + (size_t)b * NC;
    const int n0 = blockIdx.x * 128, c0 = blockIdx.y * 128;
    const int lane = threadIdx.x & 63, wave = threadIdx.x >> 6;
    const int wc = (wave >> 1) * 64, wn = (wave & 1) * 64;
    const int l15 = lane & 15, lk = (lane >> 4) * 8;

    f32x4 acc[4][4] = {};
    const u16* wrow[4]; const u16* xrow[4];
    #pragma unroll
    for (int ai = 0; ai < 4; ai++) wrow[ai] = W  + (size_t)(c0 + wc + ai * 16 + l15) * CC + lk;
    #pragma unroll
    for (int bj = 0; bj < 4; bj++) xrow[bj] = Xp + (size_t)(n0 + wn + bj * 16 + l15) * CC + lk;

    #pragma unroll 2
    for (int kc = 0; kc < 8; kc++) {
        short8 a[4], bf[4];
        #pragma unroll
        for (int ai = 0; ai < 4; ai++) a[ai]  = *(const short8*)(wrow[ai] + kc * 32);
        #pragma unroll
        for (int bj = 0; bj < 4; bj++) bf[bj] = *(const short8*)(xrow[bj] + kc * 32);
        #pragma unroll
        for (int ai = 0; ai < 4; ai++)
            #pragma unroll
            for (int bj = 0; bj < 4; bj++)
                acc[ai][bj] = __builtin_amdgcn_mfma_f32_16x16x32_bf16(a[ai], bf[bj], acc[ai][bj], 0, 0, 0);
    }

    float* Of = P.o[mod] + (size_t)b * CN;
    const float* Xr = P.xsrc[mod] + (size_t)b * XBS;
    const float* bias = P.bias[mod];
    #pragma unroll
    for (int ai = 0; ai < 4; ai++)
        #pragma unroll
        for (int r = 0; r < 4; r++) {
            const int c = c0 + wc + ai * 16 + (lane >> 4) * 4 + r;
            const float bi = bias[c];
            #pragma unroll
            for (int bj = 0; bj < 4; bj++) {
                const int n = n0 + wn + bj * 16 + l15;
                Of[(size_t)c * NN + n] = Xr[(size_t)c * NN + n] + fmaxf(acc[ai][bj][r] + bi, 0.0f);
            }
        }
}

// ---------------------------------------------------------------------------
// attention v3: 32 q-rows/block, 1024 thr (16 waves), flat grid nm*512,
// XCD-pinned: batch = bid & 7 so each XCD keeps one batch's K+Q in its L2.
// Wave w owns m in [w*128, w*128+128); K frags shared across both row groups.
// S written blocked [b][n>>3][m][n&7]; per-block col partials (deterministic).
// ---------------------------------------------------------------------------
struct AttnP { const u16* q[5]; const u16* k[5]; u16* s[5]; float* cp[5]; };

__global__ __launch_bounds__(1024) void attn_mfma3(AttnP P)
{
    const int bid = blockIdx.x;
    const int mod = bid >> 9;            // 512 blocks per module
    const int within = bid & 511;
    const int b = within & 7;            // XCD-aligned batch
    const int nblk = within >> 3;        // 0..63
    const int n0 = nblk * 32;
    const int tid = threadIdx.x, lane = tid & 63, wave = tid >> 6;
    const int l15 = lane & 15, lg = lane >> 4;

    const u16* Qt = P.q[mod] + (size_t)b * NC;
    const u16* Kt = P.k[mod] + (size_t)b * NC;

    f32x4 acc[2][8];
    #pragma unroll
    for (int g = 0; g < 2; g++)
        #pragma unroll
        for (int t = 0; t < 8; t++) acc[g][t] = (f32x4){0.f, 0.f, 0.f, 0.f};

    const u16* qp0 = Qt + (size_t)(n0 + l15) * CC + lg * 8;
    const u16* qp1 = qp0 + 16 * CC;
    const u16* kp  = Kt + (size_t)(wave * 128 + l15) * CC + lg * 8;

    #pragma unroll
    for (int kc = 0; kc < 8; kc++) {
        const short8 a0 = *(const short8*)(qp0 + kc * 32);
        const short8 a1 = *(const short8*)(qp1 + kc * 32);
        short8 bf[8];
        #pragma unroll
        for (int t = 0; t < 8; t++)
            bf[t] = *(const short8*)(kp + (size_t)t * 16 * CC + kc * 32);
        #pragma unroll
        for (int t = 0; t < 8; t++) {
            acc[0][t] = __builtin_amdgcn_mfma_f32_16x16x32_bf16(a0, bf[t], acc[0][t], 0, 0, 0);
            acc[1][t] = __builtin_amdgcn_mfma_f32_16x16x32_bf16(a1, bf[t], acc[1][t], 0, 0, 0);
        }
    }

    __shared__ float red[16][32];
    __shared__ float rowstat[32];

    // ---- row max ----
    float pm[2][4];
    #pragma unroll
    for (int g = 0; g < 2; g++)
        #pragma unroll
        for (int r = 0; r < 4; r++) {
            float m = acc[g][0][r];
            #pragma unroll
            for (int t = 1; t < 8; t++) m = fmaxf(m, acc[g][t][r]);
            #pragma unroll
            for (int o = 1; o <= 8; o <<= 1) m = fmaxf(m, __shfl_xor(m, o));
            pm[g][r] = m;
        }
    if (l15 == 0) {
        #pragma unroll
        for (int g = 0; g < 2; g++)
            #pragma unroll
            for (int r = 0; r < 4; r++) red[wave][g * 16 + lg * 4 + r] = pm[g][r];
    }
    __syncthreads();
    if (tid < 32) {
        float m = red[0][tid];
        #pragma unroll
        for (int w = 1; w < 16; w++) m = fmaxf(m, red[w][tid]);
        rowstat[tid] = m;
    }
    __syncthreads();

    float rm[2][4], ps[2][4];
    #pragma unroll
    for (int g = 0; g < 2; g++)
        #pragma unroll
        for (int r = 0; r < 4; r++) { rm[g][r] = rowstat[g * 16 + lg * 4 + r]; ps[g][r] = 0.f; }
    __syncthreads();

    // ---- exp in place + row-sum ----
    #pragma unroll
    for (int g = 0; g < 2; g++)
        #pragma unroll
        for (int t = 0; t < 8; t++)
            #pragma unroll
            for (int r = 0; r < 4; r++) {
                const float e = __expf(acc[g][t][r] - rm[g][r]);
                acc[g][t][r] = e; ps[g][r] += e;
            }
    #pragma unroll
    for (int g = 0; g < 2; g++)
        #pragma unroll
        for (int r = 0; r < 4; r++)
            #pragma unroll
            for (int o = 1; o <= 8; o <<= 1) ps[g][r] += __shfl_xor(ps[g][r], o);
    if (l15 == 0) {
        #pragma unroll
        for (int g = 0; g < 2; g++)
            #pragma unroll
            for (int r = 0; r < 4; r++) red[wave][g * 16 + lg * 4 + r] = ps[g][r];
    }
    __syncthreads();
    if (tid < 32) {
        float s = red[0][tid];
        #pragma unroll
        for (int w = 1; w < 16; w++) s += red[w][tid];
        rowstat[tid] = 1.0f / s;
    }
    __syncthreads();

    float rv[2][4];
    #pragma unroll
    for (int g = 0; g < 2; g++)
        #pragma unroll
        for (int r = 0; r < 4; r++) rv[g][r] = rowstat[g * 16 + lg * 4 + r];

    // ---- store S (blocked) + column partials ----
    u16* sb = P.s[mod] + (size_t)b * NN * NN;
    u16* sbg[2];
    #pragma unroll
    for (int g = 0; g < 2; g++)
        sbg[g] = sb + (size_t)((n0 >> 3) + g * 2 + (lg >> 1)) * (NN * 8) + (lg & 1) * 4;
    float* cpb = P.cp[mod] + ((size_t)b * 64 + nblk) * NN;

    #pragma unroll
    for (int t = 0; t < 8; t++) {
        const int m = wave * 128 + t * 16 + l15;
        float cs = 0.0f;
        #pragma unroll
        for (int g = 0; g < 2; g++) {
            const float v0 = acc[g][t][0] * rv[g][0], v1 = acc[g][t][1] * rv[g][1];
            const float v2 = acc[g][t][2] * rv[g][2], v3 = acc[g][t][3] * rv[g][3];
            ushort4 pk;
            pk.x = f2bf(v0); pk.y = f2bf(v1); pk.z = f2bf(v2); pk.w = f2bf(v3);
            *(ushort4*)&sbg[g][(size_t)m * 8] = pk;
            cs += v0 + v1 + v2 + v3;
        }
        cs += __shfl_xor(cs, 16);
        cs += __shfl_xor(cs, 32);
        if (lane < 16) cpb[m] = cs;
    }
}

// ---------------------------------------------------------------------------
// colsum[b][m] = sum_{g<64} cspart[b][g][m]
// ---------------------------------------------------------------------------
struct CsP { const float* cp[5]; float* cs[5]; };

__global__ __launch_bounds__(256) void csum_kernel(CsP P)
{
    const int z = blockIdx.y, mod = z >> 3, b = z & 7;
    const int ml = threadIdx.x & 63;
    const int m  = blockIdx.x * 64 + ml;
    const int g0 = threadIdx.x >> 6;
    float s = 0.0f;
    for (int g = g0; g < 64; g += 4)
        s += P.cp[mod][((size_t)b * 64 + g) * NN + m];
    __shared__ float red[4][64];
    red[g0][ml] = s;
    __syncthreads();
    if (threadIdx.x < 64) {
        P.cs[mod][(size_t)b * NN + blockIdx.x * 64 + threadIdx.x] =
            red[0][threadIdx.x] + red[1][threadIdx.x] +
            red[2][threadIdx.x] + red[3][threadIdx.x];
    }
}

// ---------------------------------------------------------------------------
// pv + fused Dt: tmp[c][m] = (sum_n V[c][n]*S[n][m]) / (1e-7 + colsum[m]);
// Dt[m][c] = bf16(Xt[m][c] - tmp[c][m]).  Flat grid nm*512, batch = bid&7
// (XCD-pinned); the two c-tiles of an m-tile are adjacent (S cols L2-hit).
// ---------------------------------------------------------------------------
struct PvP { const u16* v[5]; const u16* s[5]; const float* cs[5];
             const u16* xt[5]; u16* dt[5]; };

__global__ __launch_bounds__(256) void pv_mfma(PvP P)
{
    const int bid = blockIdx.x;
    const int mod = bid >> 9;
    const int within = bid & 511;
    const int b = within & 7;
    const int r2 = within >> 3;          // 0..63
    const int cy = r2 & 1, mx = r2 >> 1;
    const int m0b = mx * 64, c0 = cy * 128;
    const int lane = threadIdx.x & 63, wave = threadIdx.x >> 6;
    const int wc = (wave >> 1) * 64, wm = (wave & 1) * 32;
    const int l15 = lane & 15, lg = lane >> 4;

    const u16* Vm = P.v[mod] + (size_t)b * CN;
    const u16* Sm = P.s[mod] + (size_t)b * NN * NN;

    f32x4 acc[4][2] = {};
    const u16* vp[4]; const u16* sp[2];
    #pragma unroll
    for (int ai = 0; ai < 4; ai++)
        vp[ai] = Vm + (size_t)(c0 + wc + ai * 16 + l15) * NN + lg * 8;
    #pragma unroll
    for (int bj = 0; bj < 2; bj++)
        sp[bj] = Sm + ((size_t)lg * NN + m0b + wm + bj * 16 + l15) * 8;

    #pragma unroll 2
    for (int kc = 0; kc < 64; kc++) {
        short8 a[4], s2[2];
        #pragma unroll
        for (int ai = 0; ai < 4; ai++) { a[ai] = *(const short8*)vp[ai]; vp[ai] += 32; }
        #pragma unroll
        for (int bj = 0; bj < 2; bj++) { s2[bj] = *(const short8*)sp[bj]; sp[bj] += (size_t)4 * NN * 8; }
        #pragma unroll
        for (int ai = 0; ai < 4; ai++)
            #pragma unroll
            for (int bj = 0; bj < 2; bj++)
                acc[ai][bj] = __builtin_amdgcn_mfma_f32_16x16x32_bf16(a[ai], s2[bj], acc[ai][bj], 0, 0, 0);
    }

    const u16* Xtb = P.xt[mod] + (size_t)b * (3 * NC);
    u16* Dtb = P.dt[mod] + (size_t)b * NC;

    #pragma unroll
    for (int bj = 0; bj < 2; bj++) {
        const int m = m0b + wm + bj * 16 + l15;
        const float inv = 1.0f / (1e-7f + P.cs[mod][(size_t)b * NN + m]);
        #pragma unroll
        for (int ai = 0; ai < 4; ai++) {
            const int cb = c0 + wc + ai * 16 + lg * 4;
            const ushort4 xv = *(const ushort4*)&Xtb[(size_t)m * CC + cb];
            ushort4 pk;
            pk.x = f2bf(bf2f(xv.x) - acc[ai][bj][0] * inv);
            pk.y = f2bf(bf2f(xv.y) - acc[ai][bj][1] * inv);
            pk.z = f2bf(bf2f(xv.z) - acc[ai][bj][2] * inv);
            pk.w = f2bf(bf2f(xv.w) - acc[ai][bj][3] * inv);
            *(ushort4*)&Dtb[(size_t)m * CC + cb] = pk;
        }
    }
}

// ---------------------------------------------------------------------------
// elementwise combines
// ---------------------------------------------------------------------------
__global__ __launch_bounds__(256) void ew_update_kernel(float* __restrict__ A,
                                                        const float* __restrict__ Bv)
{
    const size_t i = ((size_t)blockIdx.x * 256 + threadIdx.x) * 4;
    float4 a = *(float4*)&A[i];
    const float4 b = *(const float4*)&Bv[i];
    a.x = tanhf(a.x * sigf(b.x));
    a.y = tanhf(a.y * sigf(b.y));
    a.z = tanhf(a.z * sigf(b.z));
    a.w = tanhf(a.w * sigf(b.w));
    *(float4*)&A[i] = a;
}

__global__ __launch_bounds__(256) void ew_final_kernel(const float* __restrict__ TU,
                                                       const float* __restrict__ SU,
                                                       const float* __restrict__ x,
                                                       float* __restrict__ OUT)
{
    const size_t i   = ((size_t)blockIdx.x * 256 + threadIdx.x) * 4;
    const size_t b   = i / CN;
    const size_t off = i - b * CN;
    const float4 mid = *(const float4*)&x[(b * 3 + 1) * CN + off];
    const float4 g   = *(const float4*)&OUT[i];
    const float4 tu  = *(const float4*)&TU[i];
    const float4 su  = *(const float4*)&SU[i];
    float4 o;
    o.x = mid.x + sigf((tu.x + su.x) * sigf(g.x)) * tanhf(g.x);
    o.y = mid.y + sigf((tu.y + su.y) * sigf(g.y)) * tanhf(g.y);
    o.z = mid.z + sigf((tu.z + su.z) * sigf(g.z)) * tanhf(g.z);
    o.w = mid.w + sigf((tu.w + su.w) * sigf(g.w)) * tanhf(g.w);
    *(float4*)&OUT[i] = o;
}

// ---------------------------------------------------------------------------
extern "C" void kernel_launch(void* const* d_in, const int* in_sizes, int n_in,
                              void* d_out, int out_size, void* d_ws, size_t ws_size,
                              hipStream_t stream)
{
    const float* x   = (const float*)d_in[0];
    const float* Wqk = (const float*)d_in[1];
    const float* Vw  = (const float*)d_in[2];
    const float* VbF = (const float*)d_in[3];
    const float* Tw  = (const float*)d_in[4];
    const float* TbF = (const float*)d_in[5];
    float* out = (float*)d_out;

    // module meta: x-side slice (K,V) and y-side slice (Q). time=0 mid=1 space=2
    const int mxs[5] = {0, 2, 0, 2, 1};
    const int mys[5] = {0, 2, 2, 0, 1};
    const int qjob[5] = {0, 1, 5, 6, 4};
    const int q_wi[7] = {0, 1, 2, 3, 4, 2, 3};
    const int q_xi[7] = {0, 2, 0, 2, 1, 2, 0};

    const size_t WSZ     = (size_t)CC * CC;
    const size_t QK_SLAB = (size_t)BB * NC;              // elems (bf16)
    const size_t S_SLAB  = (size_t)BB * NN * NN;         // elems (bf16)
    const size_t CP_SLAB = (size_t)BB * 64 * NN;         // elems (f32)
    const size_t CS_SLAB = (size_t)BB * NN;
    const size_t O_SLAB  = (size_t)BB * CN;

    const size_t base_b = 15 * WSZ * 2 + (size_t)BB * 3 * NC * 2;
    const size_t mod_b  = S_SLAB * 2 + CP_SLAB * 4 + CS_SLAB * 4 + QK_SLAB * 2 /*Dt*/;
    const size_t margin = 2u << 20;
    const size_t need_A = base_b + 12 * QK_SLAB * 2 + 5 * mod_b + 4 * O_SLAB * 4 + margin;
    const size_t need_B = base_b + 12 * QK_SLAB * 2 + 1 * mod_b + 2 * O_SLAB * 4 + margin;
    const size_t need_C = base_b +  3 * QK_SLAB * 2 + 1 * mod_b + 2 * O_SLAB * 4 + margin;

    const int tier = (ws_size >= need_A) ? 0 : (ws_size >= need_B ? 1 : 2);
    if (tier == 2 && ws_size < need_C) return;

    const int nQK = (tier <= 1) ? 7 : 2;
    const int nV  = (tier <= 1) ? 5 : 1;
    const int nM  = (tier == 0) ? 5 : 1;
    const int nO  = (tier == 0) ? 4 : 2;

    char* ws = (char*)d_ws;
    size_t off = 0;
    auto alloc = [&](size_t bytes) -> char* {
        char* p = ws + off; off += (bytes + 255) & ~255ULL; return p;
    };

    u16*   W16 = (u16*)  alloc(15 * WSZ * 2);
    u16*   Xt  = (u16*)  alloc((size_t)BB * 3 * NC * 2);
    u16*   QK  = (u16*)  alloc((size_t)nQK * QK_SLAB * 2);
    u16*   VB  = (u16*)  alloc((size_t)nV * QK_SLAB * 2);
    u16*   S   = (u16*)  alloc((size_t)nM * S_SLAB * 2);
    float* CP  = (float*)alloc((size_t)nM * CP_SLAB * 4);
    float* CS  = (float*)alloc((size_t)nM * CS_SLAB * 4);
    u16*   DT  = (u16*)  alloc((size_t)nM * QK_SLAB * 2);
    float* OB  = (float*)alloc((size_t)nO * O_SLAB * 4);

    cast_kernel<<<320, 256, 0, stream>>>(Wqk, W16);
    cast_kernel<<<320, 256, 0, stream>>>(Vw,  W16 + 5 * WSZ);
    cast_kernel<<<320, 256, 0, stream>>>(Tw,  W16 + 10 * WSZ);
    tcast_x<<<dim3(NN / 64, CC / 64, BB * 3), 256, 0, stream>>>(x, Xt);

    // per-stage tail over a module set [m0, m0+nm)
    auto run_tail = [&](int m0, int nm,
                        const u16* qv[5], const u16* kv[5], const u16* vv[5],
                        u16* sv[5], float* cpv[5], float* csv[5],
                        u16* dtv[5], float* ov[5]) {
        AttnP ap{}; CsP cp{}; PvP pp{}; TcvP tv{};
        for (int j = 0; j < nm; j++) {
            const int i = m0 + j;
            ap.q[j] = qv[j]; ap.k[j] = kv[j]; ap.s[j] = sv[j]; ap.cp[j] = cpv[j];
            cp.cp[j] = cpv[j]; cp.cs[j] = csv[j];
            pp.v[j] = vv[j]; pp.s[j] = sv[j]; pp.cs[j] = csv[j];
            pp.xt[j] = Xt + (size_t)mxs[i] * NC; pp.dt[j] = dtv[j];
            tv.w[j] = W16 + (size_t)(10 + i) * WSZ; tv.dt[j] = dtv[j];
            tv.bias[j] = TbF + (size_t)i * CC;
            tv.xsrc[j] = x + (size_t)mxs[i] * CN; tv.o[j] = ov[j];
        }
        attn_mfma3<<<dim3(nm * 512), 1024, 0, stream>>>(ap);
        csum_kernel<<<dim3(NN / 64, 8 * nm), 256, 0, stream>>>(cp);
        pv_mfma<<<dim3(nm * 512), 256, 0, stream>>>(pp);
        conv_t<<<dim3(NN / 128, CC / 128, 8 * nm), 256, 0, stream>>>(tv);
    };

    if (tier <= 1) {
        QkvP qp{};
        for (int j = 0; j < 7; j++) {
            qp.w[j] = W16 + (size_t)q_wi[j] * WSZ;
            qp.x[j] = Xt + (size_t)q_xi[j] * NC;
            qp.out[j] = QK + (size_t)j * QK_SLAB;
            qp.isv[j] = 0; qp.bias[j] = nullptr;
        }
        for (int i = 0; i < 5; i++) {
            const int j = 7 + i;
            qp.w[j] = W16 + (size_t)(5 + i) * WSZ;
            qp.x[j] = Xt + (size_t)mxs[i] * NC;
            qp.out[j] = VB + (size_t)i * QK_SLAB;
            qp.isv[j] = 1; qp.bias[j] = VbF + (size_t)i * CC;
        }
        conv_qkv<<<dim3(NN / 128, CC / 128, 96), 256, 0, stream>>>(qp);
    }

    if (tier == 0) {
        const u16* qv[5]; const u16* kv[5]; const u16* vv[5];
        u16* sv[5]; float* cpv[5]; float* csv[5]; u16* dtv[5]; float* ov[5];
        for (int i = 0; i < 5; i++) {
            qv[i] = QK + (size_t)qjob[i] * QK_SLAB;
            kv[i] = QK + (size_t)i * QK_SLAB;
            vv[i] = VB + (size_t)i * QK_SLAB;
            sv[i] = S + (size_t)i * S_SLAB;
            cpv[i] = CP + (size_t)i * CP_SLAB;
            csv[i] = CS + (size_t)i * CS_SLAB;
            dtv[i] = DT + (size_t)i * QK_SLAB;
            ov[i] = (i < 4) ? (OB + (size_t)i * O_SLAB) : out;
        }
        run_tail(0, 5, qv, kv, vv, sv, cpv, csv, dtv, ov);
        ew_update_kernel<<<4096, 256, 0, stream>>>(OB + 0 * O_SLAB, OB + 2 * O_SLAB);
        ew_update_kernel<<<4096, 256, 0, stream>>>(OB + 1 * O_SLAB, OB + 3 * O_SLAB);
        ew_final_kernel<<<4096, 256, 0, stream>>>(OB + 0 * O_SLAB, OB + 1 * O_SLAB, x, out);
        return;
    }

    auto run_mod = [&](int i, float* O) {
        const u16* Qp; const u16* Kp; const u16* Vp;
        if (tier == 1) {
            Qp = QK + (size_t)qjob[i] * QK_SLAB;
            Kp = QK + (size_t)i * QK_SLAB;
            Vp = VB + (size_t)i * QK_SLAB;
        } else {
            QkvP qp{}; int nj = 0;
            qp.w[nj] = W16 + (size_t)i * WSZ; qp.x[nj] = Xt + (size_t)mxs[i] * NC;
            qp.out[nj] = QK; qp.isv[nj] = 0; nj++;
            Qp = QK; Kp = QK;
            if (mys[i] != mxs[i]) {
                qp.w[nj] = W16 + (size_t)i * WSZ; qp.x[nj] = Xt + (size_t)mys[i] * NC;
                qp.out[nj] = QK + QK_SLAB; qp.isv[nj] = 0; nj++;
                Qp = QK + QK_SLAB;
            }
            qp.w[nj] = W16 + (size_t)(5 + i) * WSZ; qp.x[nj] = Xt + (size_t)mxs[i] * NC;
            qp.out[nj] = VB; qp.isv[nj] = 1; qp.bias[nj] = VbF + (size_t)i * CC; nj++;
            conv_qkv<<<dim3(NN / 128, CC / 128, 8 * nj), 256, 0, stream>>>(qp);
            Vp = VB;
        }
        const u16* qv[5] = {Qp}; const u16* kv[5] = {Kp}; const u16* vv[5] = {Vp};
        u16* sv[5] = {S}; float* cpv[5] = {CP}; float* csv[5] = {CS};
        u16* dtv[5] = {DT}; float* ov[5] = {O};
        run_tail(i, 1, qv, kv, vv, sv, cpv, csv, dtv, ov);
    };

    run_mod(0, OB);                                          // time_att
    run_mod(2, OB + O_SLAB);                                 // time_cor
    ew_update_kernel<<<4096, 256, 0, stream>>>(OB, OB + O_SLAB);
    run_mod(1, OB + O_SLAB);                                 // space_att
    run_mod(3, out);                                         // space_cor (d_out temp)
    ew_update_kernel<<<4096, 256, 0, stream>>>(OB + O_SLAB, out);
    run_mod(4, out);                                         // global_feat
    ew_final_kernel<<<4096, 256, 0, stream>>>(OB, OB + O_SLAB, x, out);
}

// Round 5
// 772.980 us; speedup vs baseline: 1.8921x; 1.4785x over previous
//
#include <hip/hip_runtime.h>
#include <math.h>

#define BB 8
#define CC 256
#define NN 2048

static const size_t NC  = (size_t)NN * CC;
static const size_t CN  = (size_t)CC * NN;
static const size_t XBS = 3 * CN;            // batch stride of x [B,3,C,N]

typedef unsigned short u16;
typedef __attribute__((ext_vector_type(8))) short short8;   // 8 bf16 (one MFMA frag)
typedef __attribute__((ext_vector_type(4))) float f32x4;    // MFMA acc

__device__ __forceinline__ float bf2f(u16 v) {
    union { unsigned int u; float f; } t; t.u = ((unsigned int)v) << 16; return t.f;
}
__device__ __forceinline__ u16 f2bf(float f) {
    union { float f; unsigned int u; } t; t.f = f;
    return (u16)((t.u + 0x7fffu + ((t.u >> 16) & 1u)) >> 16);
}
__device__ __forceinline__ float sigf(float x) { return 1.0f / (1.0f + expf(-x)); }

// ---------------------------------------------------------------------------
// 16x32-tiled layout: logical (r,c) of an [R][C] slab; tpr = C/32 tiles/row.
// Tile = 16 rows x 32 cols = 1KB contiguous. An MFMA fragment (16 rows x 32 k)
// is exactly one tile: lane reads at l15*32 + lg*8 -> contiguous 1KB per wave.
// ---------------------------------------------------------------------------
__device__ __forceinline__ size_t til(int r, int c, int tpr) {
    return (((size_t)((r >> 4) * tpr + (c >> 5))) << 9)
         + (size_t)((r & 15) << 5) + (size_t)(c & 31);
}

// ---------------------------------------------------------------------------
// weights fp32 [mat][256][256] -> bf16 tiled (c16,k32)
// ---------------------------------------------------------------------------
__global__ __launch_bounds__(256) void cast_w(const float* __restrict__ in,
                                              u16* __restrict__ outp)
{
    const int mat = blockIdx.y;
    const int idx = blockIdx.x * 256 + threadIdx.x;    // 0..16383
    const int c = idx >> 6, k = (idx & 63) << 2;
    const float4 v = *(const float4*)&in[(size_t)mat * (CC * CC) + (size_t)c * CC + k];
    ushort4 p;
    p.x = f2bf(v.x); p.y = f2bf(v.y); p.z = f2bf(v.z); p.w = f2bf(v.w);
    *(ushort4*)&outp[(size_t)mat * (CC * CC) + til(c, k, CC / 32)] = p;
}

// ---------------------------------------------------------------------------
// transpose-cast x: Xt[z] tiled(n16,c32) = bf16(x[z][c][n]); z = b*3+slice
// ---------------------------------------------------------------------------
__global__ __launch_bounds__(256) void tcast_x(const float* __restrict__ in,
                                               u16* __restrict__ out)
{
    const int z = blockIdx.z;
    const float* I = in + (size_t)z * CN;
    u16* O = out + (size_t)z * NC;
    const int c0 = blockIdx.y * 64, n0 = blockIdx.x * 64;
    const int tx = threadIdx.x & 15, ty = threadIdx.x >> 4;

    __shared__ float t[64][68];

    #pragma unroll
    for (int cc = 0; cc < 64; cc += 16) {
        const int c = ty + cc;
        *(float4*)&t[c][tx * 4] = *(const float4*)&I[(size_t)(c0 + c) * NN + n0 + tx * 4];
    }
    __syncthreads();
    #pragma unroll
    for (int nn2 = 0; nn2 < 64; nn2 += 16) {
        const int n = n0 + ty + nn2;
        const int c = c0 + tx * 4;
        ushort4 p;
        p.x = f2bf(t[tx * 4 + 0][ty + nn2]);
        p.y = f2bf(t[tx * 4 + 1][ty + nn2]);
        p.z = f2bf(t[tx * 4 + 2][ty + nn2]);
        p.w = f2bf(t[tx * 4 + 3][ty + nn2]);
        *(ushort4*)&O[til(n, c, 8)] = p;
    }
}

// ---------------------------------------------------------------------------
// Q/K/V conv via MFMA, table-driven, all operands tiled.
// isv=0: A=W(c rows), B=Xt(n rows); out tiled(n16,c32)   [Q/K]
// isv=1: A=Xt(n rows), B=W(c rows); out tiled(c16,n32)+bias [V]
// z = job*8 + b.  Tile 128c x 128n, 4 waves, 4x4 frags.
// ---------------------------------------------------------------------------
struct QkvP {
    const u16* w[12]; const u16* x[12]; u16* out[12];
    const float* bias[12]; int isv[12];
};

__global__ __launch_bounds__(256) void conv_qkv(QkvP P)
{
    const int z = blockIdx.z, job = z >> 3, b = z & 7;
    const int isv = P.isv[job];
    const u16* Wp = P.w[job];
    const u16* Xp = P.x[job] + (size_t)b * (3 * NC);
    const int n0 = blockIdx.x * 128, c0 = blockIdx.y * 128;
    const int lane = threadIdx.x & 63, wave = threadIdx.x >> 6;
    const int l15 = lane & 15, lg = lane >> 4;
    const int rA = (wave >> 1) * 64, rB = (wave & 1) * 64;

    const u16* Ab = isv ? Xp : Wp;
    const u16* Bb = isv ? Wp : Xp;
    const int Ar0 = (isv ? n0 : c0) + rA;
    const int Br0 = (isv ? c0 : n0) + rB;

    const u16* ap[4]; const u16* bp[4];
    #pragma unroll
    for (int i = 0; i < 4; i++) {
        ap[i] = Ab + til(Ar0 + i * 16 + l15, lg * 8, 8);
        bp[i] = Bb + til(Br0 + i * 16 + l15, lg * 8, 8);
    }

    f32x4 acc[4][4] = {};
    #pragma unroll 2
    for (int kc = 0; kc < 8; kc++) {
        short8 av[4], bv[4];
        #pragma unroll
        for (int i = 0; i < 4; i++) av[i] = *(const short8*)(ap[i] + kc * 512);
        #pragma unroll
        for (int i = 0; i < 4; i++) bv[i] = *(const short8*)(bp[i] + kc * 512);
        #pragma unroll
        for (int i = 0; i < 4; i++)
            #pragma unroll
            for (int j = 0; j < 4; j++)
                acc[i][j] = __builtin_amdgcn_mfma_f32_16x16x32_bf16(av[i], bv[j], acc[i][j], 0, 0, 0);
    }

    if (!isv) {
        u16* Ot = P.out[job] + (size_t)b * NC;
        #pragma unroll
        for (int i = 0; i < 4; i++) {
            const int c = c0 + rA + i * 16 + lg * 4;    // reg-packed dim
            #pragma unroll
            for (int j = 0; j < 4; j++) {
                const int n = n0 + rB + j * 16 + l15;
                ushort4 p;
                p.x = f2bf(acc[i][j][0]); p.y = f2bf(acc[i][j][1]);
                p.z = f2bf(acc[i][j][2]); p.w = f2bf(acc[i][j][3]);
                *(ushort4*)&Ot[til(n, c, 8)] = p;
            }
        }
    } else {
        u16* Ov = P.out[job] + (size_t)b * CN;
        const float* bias = P.bias[job];
        #pragma unroll
        for (int j = 0; j < 4; j++) {
            const int c = c0 + rB + j * 16 + l15;
            const float bi = bias[c];
            #pragma unroll
            for (int i = 0; i < 4; i++) {
                const int n = n0 + rA + i * 16 + lg * 4;  // reg-packed dim
                ushort4 p;
                p.x = f2bf(acc[i][j][0] + bi); p.y = f2bf(acc[i][j][1] + bi);
                p.z = f2bf(acc[i][j][2] + bi); p.w = f2bf(acc[i][j][3] + bi);
                *(ushort4*)&Ov[til(c, n, 64)] = p;
            }
        }
    }
}

// ---------------------------------------------------------------------------
// T-stage conv: O[c][n] = xsrc[c][n] + relu(sum_k W[c][k]*Dt[n][k] + bias[c])
// W tiled(c16,k32), Dt tiled(n16,c32). z = b (single module per launch).
// ---------------------------------------------------------------------------
__global__ __launch_bounds__(256) void conv_t(
    const u16* __restrict__ W, const u16* __restrict__ Dt,
    const float* __restrict__ bias, const float* __restrict__ xsrc,
    float* __restrict__ Ofull)
{
    const int b = blockIdx.z;
    const u16* Xp = Dt + (size_t)b * NC;
    const int n0 = blockIdx.x * 128, c0 = blockIdx.y * 128;
    const int lane = threadIdx.x & 63, wave = threadIdx.x >> 6;
    const int l15 = lane & 15, lg = lane >> 4;
    const int wc = (wave >> 1) * 64, wn = (wave & 1) * 64;

    const u16* ap[4]; const u16* bp[4];
    #pragma unroll
    for (int i = 0; i < 4; i++) {
        ap[i] = W  + til(c0 + wc + i * 16 + l15, lg * 8, 8);
        bp[i] = Xp + til(n0 + wn + i * 16 + l15, lg * 8, 8);
    }

    f32x4 acc[4][4] = {};
    #pragma unroll 2
    for (int kc = 0; kc < 8; kc++) {
        short8 av[4], bv[4];
        #pragma unroll
        for (int i = 0; i < 4; i++) av[i] = *(const short8*)(ap[i] + kc * 512);
        #pragma unroll
        for (int i = 0; i < 4; i++) bv[i] = *(const short8*)(bp[i] + kc * 512);
        #pragma unroll
        for (int i = 0; i < 4; i++)
            #pragma unroll
            for (int j = 0; j < 4; j++)
                acc[i][j] = __builtin_amdgcn_mfma_f32_16x16x32_bf16(av[i], bv[j], acc[i][j], 0, 0, 0);
    }

    float* Of = Ofull + (size_t)b * CN;
    const float* Xr = xsrc + (size_t)b * XBS;
    #pragma unroll
    for (int i = 0; i < 4; i++)
        #pragma unroll
        for (int r = 0; r < 4; r++) {
            const int c = c0 + wc + i * 16 + lg * 4 + r;
            const float bi = bias[c];
            #pragma unroll
            for (int j = 0; j < 4; j++) {
                const int n = n0 + wn + j * 16 + l15;
                Of[(size_t)c * NN + n] = Xr[(size_t)c * NN + n] + fmaxf(acc[i][j][r] + bi, 0.0f);
            }
        }
}

// ---------------------------------------------------------------------------
// attention: 32 q-rows/block, 1024 thr (16 waves), 512 blocks (batch = bid&7,
// XCD-pinned). Q/K tiled -> all fragment loads contiguous 1KB.
// S written blocked [b][n>>3][m][n&7]; per-block col partials (deterministic).
// ---------------------------------------------------------------------------
__global__ __launch_bounds__(1024) void attn_mfma4(
    const u16* __restrict__ Q, const u16* __restrict__ K,
    u16* __restrict__ Sout, float* __restrict__ CPb)
{
    const int bid = blockIdx.x;
    const int b = bid & 7;
    const int nblk = bid >> 3;           // 0..63
    const int n0 = nblk * 32;
    const int tid = threadIdx.x, lane = tid & 63, wave = tid >> 6;
    const int l15 = lane & 15, lg = lane >> 4;

    const u16* Qt = Q + (size_t)b * NC;
    const u16* Kt = K + (size_t)b * NC;

    f32x4 acc[2][8];
    #pragma unroll
    for (int g = 0; g < 2; g++)
        #pragma unroll
        for (int t = 0; t < 8; t++) acc[g][t] = (f32x4){0.f, 0.f, 0.f, 0.f};

    const u16* qb0 = Qt + til(n0 + l15,      lg * 8, 8);
    const u16* qb1 = Qt + til(n0 + 16 + l15, lg * 8, 8);
    const u16* kb  = Kt + til(wave * 128 + l15, lg * 8, 8);

    #pragma unroll
    for (int kc = 0; kc < 8; kc++) {
        const short8 a0 = *(const short8*)(qb0 + kc * 512);
        const short8 a1 = *(const short8*)(qb1 + kc * 512);
        short8 bf[8];
        #pragma unroll
        for (int t = 0; t < 8; t++)
            bf[t] = *(const short8*)(kb + t * 4096 + kc * 512);
        #pragma unroll
        for (int t = 0; t < 8; t++) {
            acc[0][t] = __builtin_amdgcn_mfma_f32_16x16x32_bf16(a0, bf[t], acc[0][t], 0, 0, 0);
            acc[1][t] = __builtin_amdgcn_mfma_f32_16x16x32_bf16(a1, bf[t], acc[1][t], 0, 0, 0);
        }
    }

    __shared__ float red[16][32];
    __shared__ float rowstat[32];

    // ---- row max ----
    float pm[2][4];
    #pragma unroll
    for (int g = 0; g < 2; g++)
        #pragma unroll
        for (int r = 0; r < 4; r++) {
            float m = acc[g][0][r];
            #pragma unroll
            for (int t = 1; t < 8; t++) m = fmaxf(m, acc[g][t][r]);
            #pragma unroll
            for (int o = 1; o <= 8; o <<= 1) m = fmaxf(m, __shfl_xor(m, o));
            pm[g][r] = m;
        }
    if (l15 == 0) {
        #pragma unroll
        for (int g = 0; g < 2; g++)
            #pragma unroll
            for (int r = 0; r < 4; r++) red[wave][g * 16 + lg * 4 + r] = pm[g][r];
    }
    __syncthreads();
    if (tid < 32) {
        float m = red[0][tid];
        #pragma unroll
        for (int w = 1; w < 16; w++) m = fmaxf(m, red[w][tid]);
        rowstat[tid] = m;
    }
    __syncthreads();

    float rm[2][4], ps[2][4];
    #pragma unroll
    for (int g = 0; g < 2; g++)
        #pragma unroll
        for (int r = 0; r < 4; r++) { rm[g][r] = rowstat[g * 16 + lg * 4 + r]; ps[g][r] = 0.f; }
    __syncthreads();

    // ---- exp in place + row-sum ----
    #pragma unroll
    for (int g = 0; g < 2; g++)
        #pragma unroll
        for (int t = 0; t < 8; t++)
            #pragma unroll
            for (int r = 0; r < 4; r++) {
                const float e = __expf(acc[g][t][r] - rm[g][r]);
                acc[g][t][r] = e; ps[g][r] += e;
            }
    #pragma unroll
    for (int g = 0; g < 2; g++)
        #pragma unroll
        for (int r = 0; r < 4; r++)
            #pragma unroll
            for (int o = 1; o <= 8; o <<= 1) ps[g][r] += __shfl_xor(ps[g][r], o);
    if (l15 == 0) {
        #pragma unroll
        for (int g = 0; g < 2; g++)
            #pragma unroll
            for (int r = 0; r < 4; r++) red[wave][g * 16 + lg * 4 + r] = ps[g][r];
    }
    __syncthreads();
    if (tid < 32) {
        float s = red[0][tid];
        #pragma unroll
        for (int w = 1; w < 16; w++) s += red[w][tid];
        rowstat[tid] = 1.0f / s;
    }
    __syncthreads();

    float rv[2][4];
    #pragma unroll
    for (int g = 0; g < 2; g++)
        #pragma unroll
        for (int r = 0; r < 4; r++) rv[g][r] = rowstat[g * 16 + lg * 4 + r];

    // ---- store S (blocked) + column partials ----
    u16* sb = Sout + (size_t)b * NN * NN;
    u16* sbg[2];
    #pragma unroll
    for (int g = 0; g < 2; g++)
        sbg[g] = sb + (size_t)((n0 >> 3) + g * 2 + (lg >> 1)) * (NN * 8) + (lg & 1) * 4;
    float* cpb = CPb + ((size_t)b * 64 + nblk) * NN;

    #pragma unroll
    for (int t = 0; t < 8; t++) {
        const int m = wave * 128 + t * 16 + l15;
        float cs = 0.0f;
        #pragma unroll
        for (int g = 0; g < 2; g++) {
            const float v0 = acc[g][t][0] * rv[g][0], v1 = acc[g][t][1] * rv[g][1];
            const float v2 = acc[g][t][2] * rv[g][2], v3 = acc[g][t][3] * rv[g][3];
            ushort4 pk;
            pk.x = f2bf(v0); pk.y = f2bf(v1); pk.z = f2bf(v2); pk.w = f2bf(v3);
            *(ushort4*)&sbg[g][(size_t)m * 8] = pk;
            cs += v0 + v1 + v2 + v3;
        }
        cs += __shfl_xor(cs, 16);
        cs += __shfl_xor(cs, 32);
        if (lane < 16) cpb[m] = cs;
    }
}

// ---------------------------------------------------------------------------
// colsum[b][m] = sum_{g<64} cspart[b][g][m]
// ---------------------------------------------------------------------------
__global__ __launch_bounds__(256) void csum_kernel(const float* __restrict__ cp,
                                                   float* __restrict__ cs)
{
    const int b  = blockIdx.y;
    const int ml = threadIdx.x & 63;
    const int m  = blockIdx.x * 64 + ml;
    const int g0 = threadIdx.x >> 6;
    float s = 0.0f;
    for (int g = g0; g < 64; g += 4)
        s += cp[((size_t)b * 64 + g) * NN + m];
    __shared__ float red[4][64];
    red[g0][ml] = s;
    __syncthreads();
    if (threadIdx.x < 64) {
        cs[(size_t)b * NN + blockIdx.x * 64 + threadIdx.x] =
            red[0][threadIdx.x] + red[1][threadIdx.x] +
            red[2][threadIdx.x] + red[3][threadIdx.x];
    }
}

// ---------------------------------------------------------------------------
// pv + fused Dt: tmp[c][m] = (sum_n V[c][n]*S[n][m]) / (1e-7+colsum[m]);
// Dt tiled(m16,c32) = bf16(Xt[m][c] - tmp[c][m]).  512 blocks, batch = bid&7.
// V tiled(c16,n32) -> contiguous A-frags; S blocked -> 256B B-frag segments.
// ---------------------------------------------------------------------------
__global__ __launch_bounds__(256) void pv_mfma(
    const u16* __restrict__ V, const u16* __restrict__ S,
    const float* __restrict__ CSb, const u16* __restrict__ Xts,
    u16* __restrict__ DTo)
{
    const int bid = blockIdx.x;
    const int b = bid & 7;
    const int r2 = bid >> 3;             // 0..63
    const int cy = r2 & 1, mx = r2 >> 1;
    const int m0b = mx * 64, c0 = cy * 128;
    const int lane = threadIdx.x & 63, wave = threadIdx.x >> 6;
    const int wc = (wave >> 1) * 64, wm = (wave & 1) * 32;
    const int l15 = lane & 15, lg = lane >> 4;

    const u16* Vm = V + (size_t)b * CN;
    const u16* Sm = S + (size_t)b * NN * NN;

    f32x4 acc[4][2] = {};
    const u16* vp[4]; const u16* sp[2];
    #pragma unroll
    for (int ai = 0; ai < 4; ai++)
        vp[ai] = Vm + til(c0 + wc + ai * 16 + l15, lg * 8, 64);
    #pragma unroll
    for (int bj = 0; bj < 2; bj++)
        sp[bj] = Sm + ((size_t)lg * NN + m0b + wm + bj * 16 + l15) * 8;

    #pragma unroll 2
    for (int kc = 0; kc < 64; kc++) {
        short8 a[4], s2[2];
        #pragma unroll
        for (int ai = 0; ai < 4; ai++) { a[ai] = *(const short8*)vp[ai]; vp[ai] += 512; }
        #pragma unroll
        for (int bj = 0; bj < 2; bj++) { s2[bj] = *(const short8*)sp[bj]; sp[bj] += (size_t)4 * NN * 8; }
        #pragma unroll
        for (int ai = 0; ai < 4; ai++)
            #pragma unroll
            for (int bj = 0; bj < 2; bj++)
                acc[ai][bj] = __builtin_amdgcn_mfma_f32_16x16x32_bf16(a[ai], s2[bj], acc[ai][bj], 0, 0, 0);
    }

    const u16* Xtb = Xts + (size_t)b * (3 * NC);
    u16* Dtb = DTo + (size_t)b * NC;

    #pragma unroll
    for (int bj = 0; bj < 2; bj++) {
        const int m = m0b + wm + bj * 16 + l15;
        const float inv = 1.0f / (1e-7f + CSb[(size_t)b * NN + m]);
        #pragma unroll
        for (int ai = 0; ai < 4; ai++) {
            const int c = c0 + wc + ai * 16 + lg * 4;   // reg-packed dim
            const size_t ad = til(m, c, 8);
            const ushort4 xv = *(const ushort4*)&Xtb[ad];
            ushort4 pk;
            pk.x = f2bf(bf2f(xv.x) - acc[ai][bj][0] * inv);
            pk.y = f2bf(bf2f(xv.y) - acc[ai][bj][1] * inv);
            pk.z = f2bf(bf2f(xv.z) - acc[ai][bj][2] * inv);
            pk.w = f2bf(bf2f(xv.w) - acc[ai][bj][3] * inv);
            *(ushort4*)&Dtb[ad] = pk;
        }
    }
}

// ---------------------------------------------------------------------------
// elementwise combines
// ---------------------------------------------------------------------------
__global__ __launch_bounds__(256) void ew_update_kernel(float* __restrict__ A,
                                                        const float* __restrict__ Bv)
{
    const size_t i = ((size_t)blockIdx.x * 256 + threadIdx.x) * 4;
    float4 a = *(float4*)&A[i];
    const float4 b = *(const float4*)&Bv[i];
    a.x = tanhf(a.x * sigf(b.x));
    a.y = tanhf(a.y * sigf(b.y));
    a.z = tanhf(a.z * sigf(b.z));
    a.w = tanhf(a.w * sigf(b.w));
    *(float4*)&A[i] = a;
}

__global__ __launch_bounds__(256) void ew_final_kernel(const float* __restrict__ TU,
                                                       const float* __restrict__ SU,
                                                       const float* __restrict__ x,
                                                       float* __restrict__ OUT)
{
    const size_t i   = ((size_t)blockIdx.x * 256 + threadIdx.x) * 4;
    const size_t b   = i / CN;
    const size_t off = i - b * CN;
    const float4 mid = *(const float4*)&x[(b * 3 + 1) * CN + off];
    const float4 g   = *(const float4*)&OUT[i];
    const float4 tu  = *(const float4*)&TU[i];
    const float4 su  = *(const float4*)&SU[i];
    float4 o;
    o.x = mid.x + sigf((tu.x + su.x) * sigf(g.x)) * tanhf(g.x);
    o.y = mid.y + sigf((tu.y + su.y) * sigf(g.y)) * tanhf(g.y);
    o.z = mid.z + sigf((tu.z + su.z) * sigf(g.z)) * tanhf(g.z);
    o.w = mid.w + sigf((tu.w + su.w) * sigf(g.w)) * tanhf(g.w);
    *(float4*)&OUT[i] = o;
}

// ---------------------------------------------------------------------------
extern "C" void kernel_launch(void* const* d_in, const int* in_sizes, int n_in,
                              void* d_out, int out_size, void* d_ws, size_t ws_size,
                              hipStream_t stream)
{
    const float* x   = (const float*)d_in[0];
    const float* Wqk = (const float*)d_in[1];
    const float* Vw  = (const float*)d_in[2];
    const float* VbF = (const float*)d_in[3];
    const float* Tw  = (const float*)d_in[4];
    const float* TbF = (const float*)d_in[5];
    float* out = (float*)d_out;

    // module meta: x-side slice (K,V) and y-side slice (Q). time=0 mid=1 space=2
    const int mxs[5] = {0, 2, 0, 2, 1};
    const int mys[5] = {0, 2, 2, 0, 1};
    const int qjob[5] = {0, 1, 5, 6, 4};
    const int q_wi[7] = {0, 1, 2, 3, 4, 2, 3};
    const int q_xi[7] = {0, 2, 0, 2, 1, 2, 0};

    const size_t WSZ     = (size_t)CC * CC;
    const size_t QK_SLAB = (size_t)BB * NC;              // elems (bf16)
    const size_t S_SLAB  = (size_t)BB * NN * NN;         // elems (bf16)
    const size_t CP_SLAB = (size_t)BB * 64 * NN;         // elems (f32)
    const size_t CS_SLAB = (size_t)BB * NN;
    const size_t O_SLAB  = (size_t)BB * CN;

    const size_t base_b = 15 * WSZ * 2 + (size_t)BB * 3 * NC * 2;
    const size_t mod_b  = S_SLAB * 2 + CP_SLAB * 4 + CS_SLAB * 4 + QK_SLAB * 2 /*Dt*/;
    const size_t margin = 2u << 20;
    const size_t need_1 = base_b + 12 * QK_SLAB * 2 + mod_b + 2 * O_SLAB * 4 + margin;
    const size_t need_2 = base_b +  3 * QK_SLAB * 2 + mod_b + 2 * O_SLAB * 4 + margin;

    const int tier = (ws_size >= need_1) ? 1 : 2;
    if (tier == 2 && ws_size < need_2) return;

    const int nQK = (tier == 1) ? 7 : 2;
    const int nV  = (tier == 1) ? 5 : 1;

    char* ws = (char*)d_ws;
    size_t off = 0;
    auto alloc = [&](size_t bytes) -> char* {
        char* p = ws + off; off += (bytes + 255) & ~255ULL; return p;
    };

    u16*   W16 = (u16*)  alloc(15 * WSZ * 2);
    u16*   Xt  = (u16*)  alloc((size_t)BB * 3 * NC * 2);
    u16*   QK  = (u16*)  alloc((size_t)nQK * QK_SLAB * 2);
    u16*   VB  = (u16*)  alloc((size_t)nV * QK_SLAB * 2);
    u16*   S   = (u16*)  alloc(S_SLAB * 2);
    float* CP  = (float*)alloc(CP_SLAB * 4);
    float* CS  = (float*)alloc(CS_SLAB * 4);
    u16*   DT  = (u16*)  alloc(QK_SLAB * 2);
    float* OB  = (float*)alloc(2 * O_SLAB * 4);

    cast_w<<<dim3(64, 5), 256, 0, stream>>>(Wqk, W16);
    cast_w<<<dim3(64, 5), 256, 0, stream>>>(Vw,  W16 + 5 * WSZ);
    cast_w<<<dim3(64, 5), 256, 0, stream>>>(Tw,  W16 + 10 * WSZ);
    tcast_x<<<dim3(NN / 64, CC / 64, BB * 3), 256, 0, stream>>>(x, Xt);

    if (tier == 1) {
        QkvP qp{};
        for (int j = 0; j < 7; j++) {
            qp.w[j] = W16 + (size_t)q_wi[j] * WSZ;
            qp.x[j] = Xt + (size_t)q_xi[j] * NC;
            qp.out[j] = QK + (size_t)j * QK_SLAB;
            qp.isv[j] = 0; qp.bias[j] = nullptr;
        }
        for (int i = 0; i < 5; i++) {
            const int j = 7 + i;
            qp.w[j] = W16 + (size_t)(5 + i) * WSZ;
            qp.x[j] = Xt + (size_t)mxs[i] * NC;
            qp.out[j] = VB + (size_t)i * QK_SLAB;
            qp.isv[j] = 1; qp.bias[j] = VbF + (size_t)i * CC;
        }
        conv_qkv<<<dim3(NN / 128, CC / 128, 96), 256, 0, stream>>>(qp);
    }

    auto run_mod = [&](int i, float* O) {
        const u16* Qp; const u16* Kp; const u16* Vp;
        if (tier == 1) {
            Qp = QK + (size_t)qjob[i] * QK_SLAB;
            Kp = QK + (size_t)i * QK_SLAB;
            Vp = VB + (size_t)i * QK_SLAB;
        } else {
            QkvP qp{}; int nj = 0;
            qp.w[nj] = W16 + (size_t)i * WSZ; qp.x[nj] = Xt + (size_t)mxs[i] * NC;
            qp.out[nj] = QK; qp.isv[nj] = 0; nj++;
            Qp = QK; Kp = QK;
            if (mys[i] != mxs[i]) {
                qp.w[nj] = W16 + (size_t)i * WSZ; qp.x[nj] = Xt + (size_t)mys[i] * NC;
                qp.out[nj] = QK + QK_SLAB; qp.isv[nj] = 0; nj++;
                Qp = QK + QK_SLAB;
            }
            qp.w[nj] = W16 + (size_t)(5 + i) * WSZ; qp.x[nj] = Xt + (size_t)mxs[i] * NC;
            qp.out[nj] = VB; qp.isv[nj] = 1; qp.bias[nj] = VbF + (size_t)i * CC; nj++;
            conv_qkv<<<dim3(NN / 128, CC / 128, 8 * nj), 256, 0, stream>>>(qp);
            Vp = VB;
        }
        attn_mfma4<<<512, 1024, 0, stream>>>(Qp, Kp, S, CP);
        csum_kernel<<<dim3(NN / 64, BB), 256, 0, stream>>>(CP, CS);
        pv_mfma<<<512, 256, 0, stream>>>(Vp, S, CS, Xt + (size_t)mxs[i] * NC, DT);
        conv_t<<<dim3(NN / 128, CC / 128, BB), 256, 0, stream>>>(
            W16 + (size_t)(10 + i) * WSZ, DT, TbF + (size_t)i * CC,
            x + (size_t)mxs[i] * CN, O);
    };

    run_mod(0, OB);                                          // time_att
    run_mod(2, OB + O_SLAB);                                 // time_cor
    ew_update_kernel<<<4096, 256, 0, stream>>>(OB, OB + O_SLAB);
    run_mod(1, OB + O_SLAB);                                 // space_att
    run_mod(3, out);                                         // space_cor (d_out temp)
    ew_update_kernel<<<4096, 256, 0, stream>>>(OB + O_SLAB, out);
    run_mod(4, out);                                         // global_feat
    ew_final_kernel<<<4096, 256, 0, stream>>>(OB, OB + O_SLAB, x, out);
}